// Round 1
// baseline (293.133 us; speedup 1.0000x reference)
//
#include <hip/hip_runtime.h>
#include <hip/hip_bf16.h>

namespace {

constexpr int S = 2048;
constexpr int D = 64;
constexpr int NH = 12;
constexpr int NB = 2;
constexpr int BH = NB * NH;   // 24
constexpr int QT = 64;        // q rows per block
constexpr int KT = 64;        // keys per tile
constexpr int NKT = S / KT;   // 32
constexpr int PAD = 72;       // LDS row stride in ushorts (+16B pad -> 2-way max)

typedef __attribute__((ext_vector_type(8))) __bf16 bf16x8;
typedef __attribute__((ext_vector_type(4))) float  f32x4;
typedef __attribute__((ext_vector_type(4))) unsigned short u16x4;

__device__ inline unsigned short f2bf(float f) {
    // round-to-nearest-even; inputs are finite random normals (no NaN/Inf)
    unsigned int u = __float_as_uint(f);
    u += 0x7fffu + ((u >> 16) & 1u);
    return (unsigned short)(u >> 16);
}

__global__ __launch_bounds__(256, 2)
void sdpa_kernel(const float* __restrict__ q,
                 const float* __restrict__ k,
                 const float* __restrict__ v,
                 float* __restrict__ out,
                 float* __restrict__ attn) {
    __shared__ unsigned short Qs[QT][PAD];
    __shared__ unsigned short Ks[KT][PAD];
    __shared__ unsigned short Vt[D][PAD];   // V transposed: Vt[d][key]
    __shared__ unsigned short Ps[QT][PAD];  // normalized probs (bf16)

    const int bh  = blockIdx.y;
    const int q0  = blockIdx.x * QT;
    const int tid = threadIdx.x;
    const int wid  = tid >> 6;      // wave 0..3, owns q rows [wid*16, wid*16+16)
    const int lane = tid & 63;
    const int g    = lane >> 4;     // 16-lane group 0..3
    const int r16  = lane & 15;

    const float* qg = q + ((size_t)bh * S + q0) * D;
    const float* kg = k + (size_t)bh * S * D;
    const float* vg = v + (size_t)bh * S * D;
    float* attng = attn + ((size_t)bh * S + q0) * S;
    float* outg  = out  + ((size_t)bh * S + q0) * D;

    // ---- stage Q tile (QT x D) fp32 -> bf16 LDS ----
    for (int i = tid; i < QT * D / 4; i += 256) {
        int r = (i * 4) >> 6;
        int c = (i * 4) & 63;
        float4 f = *reinterpret_cast<const float4*>(qg + r * D + c);
        u16x4 w = { f2bf(f.x), f2bf(f.y), f2bf(f.z), f2bf(f.w) };
        *reinterpret_cast<u16x4*>(&Qs[r][c]) = w;
    }
    __syncthreads();

    // Q A-fragments, held in registers for the whole kernel.
    // A layout (16x16x32): lane holds A[row = lane&15][k = (lane>>4)*8 + j]
    const bf16x8 aQ0 = *(const bf16x8*)&Qs[wid * 16 + r16][g * 8];
    const bf16x8 aQ1 = *(const bf16x8*)&Qs[wid * 16 + r16][32 + g * 8];

    // ================= phase 1: row sums of exp(scores) =================
    float rs[4] = {0.f, 0.f, 0.f, 0.f};   // rows (g*4 + e) of this wave's strip

    for (int kt = 0; kt < NKT; ++kt) {
        __syncthreads();   // previous Ks fully consumed
        const float* ktg = kg + (size_t)kt * KT * D;
        for (int i = tid; i < KT * D / 4; i += 256) {
            int r = (i * 4) >> 6;
            int c = (i * 4) & 63;
            float4 f = *reinterpret_cast<const float4*>(ktg + r * D + c);
            u16x4 w = { f2bf(f.x), f2bf(f.y), f2bf(f.z), f2bf(f.w) };
            *reinterpret_cast<u16x4*>(&Ks[r][c]) = w;
        }
        __syncthreads();

        #pragma unroll
        for (int cf = 0; cf < 4; ++cf) {
            // B layout: lane holds B[k = (lane>>4)*8 + j][col = lane&15]; B = K^T
            bf16x8 b0 = *(const bf16x8*)&Ks[cf * 16 + r16][g * 8];
            bf16x8 b1 = *(const bf16x8*)&Ks[cf * 16 + r16][32 + g * 8];
            f32x4 acc = {0.f, 0.f, 0.f, 0.f};
            acc = __builtin_amdgcn_mfma_f32_16x16x32_bf16(aQ0, b0, acc, 0, 0, 0);
            acc = __builtin_amdgcn_mfma_f32_16x16x32_bf16(aQ1, b1, acc, 0, 0, 0);
            #pragma unroll
            for (int e = 0; e < 4; ++e)
                rs[e] += __expf(acc[e] * (1.0f / 64.0f));
        }
    }
    // reduce across the 16 lanes of each group (cols live across lane&15)
    #pragma unroll
    for (int m = 1; m <= 8; m <<= 1) {
        #pragma unroll
        for (int e = 0; e < 4; ++e)
            rs[e] += __shfl_xor(rs[e], m, 64);
    }
    float inv[4];
    #pragma unroll
    for (int e = 0; e < 4; ++e) inv[e] = 1.0f / rs[e];

    // ====== phase 2: recompute scores, write attn, accumulate PV ======
    f32x4 oacc[4];
    #pragma unroll
    for (int n = 0; n < 4; ++n) oacc[n] = {0.f, 0.f, 0.f, 0.f};

    for (int kt = 0; kt < NKT; ++kt) {
        __syncthreads();
        const float* ktg = kg + (size_t)kt * KT * D;
        const float* vtg = vg + (size_t)kt * KT * D;
        for (int i = tid; i < KT * D / 4; i += 256) {
            int r = (i * 4) >> 6;
            int c = (i * 4) & 63;
            float4 f = *reinterpret_cast<const float4*>(ktg + r * D + c);
            u16x4 w = { f2bf(f.x), f2bf(f.y), f2bf(f.z), f2bf(f.w) };
            *reinterpret_cast<u16x4*>(&Ks[r][c]) = w;
            float4 fv = *reinterpret_cast<const float4*>(vtg + r * D + c);
            Vt[c + 0][r] = f2bf(fv.x);   // transposed store
            Vt[c + 1][r] = f2bf(fv.y);
            Vt[c + 2][r] = f2bf(fv.z);
            Vt[c + 3][r] = f2bf(fv.w);
        }
        __syncthreads();

        // QK^T recompute; C layout: lane holds C[row=(lane>>4)*4+e][col=lane&15]
        #pragma unroll
        for (int cf = 0; cf < 4; ++cf) {
            bf16x8 b0 = *(const bf16x8*)&Ks[cf * 16 + r16][g * 8];
            bf16x8 b1 = *(const bf16x8*)&Ks[cf * 16 + r16][32 + g * 8];
            f32x4 acc = {0.f, 0.f, 0.f, 0.f};
            acc = __builtin_amdgcn_mfma_f32_16x16x32_bf16(aQ0, b0, acc, 0, 0, 0);
            acc = __builtin_amdgcn_mfma_f32_16x16x32_bf16(aQ1, b1, acc, 0, 0, 0);
            #pragma unroll
            for (int e = 0; e < 4; ++e) {
                float p = __expf(acc[e] * (1.0f / 64.0f)) * inv[e];
                int qr = wid * 16 + g * 4 + e;
                attng[(size_t)qr * S + (size_t)kt * KT + cf * 16 + r16] = p;
                Ps[qr][cf * 16 + r16] = f2bf(p);   // wave-local rows only
            }
        }
        // PV: A = P (wave-local rows, just written — same-wave LDS dep, in order)
        bf16x8 aP0 = *(const bf16x8*)&Ps[wid * 16 + r16][g * 8];
        bf16x8 aP1 = *(const bf16x8*)&Ps[wid * 16 + r16][32 + g * 8];
        #pragma unroll
        for (int n = 0; n < 4; ++n) {
            // B = V: lane holds V[key=(lane>>4)*8+j][d = n*16 + lane&15] = Vt[d][key]
            bf16x8 bv0 = *(const bf16x8*)&Vt[n * 16 + r16][g * 8];
            bf16x8 bv1 = *(const bf16x8*)&Vt[n * 16 + r16][32 + g * 8];
            oacc[n] = __builtin_amdgcn_mfma_f32_16x16x32_bf16(aP0, bv0, oacc[n], 0, 0, 0);
            oacc[n] = __builtin_amdgcn_mfma_f32_16x16x32_bf16(aP1, bv1, oacc[n], 0, 0, 0);
        }
    }

    // ---- epilogue: write out tile ----
    #pragma unroll
    for (int n = 0; n < 4; ++n) {
        #pragma unroll
        for (int e = 0; e < 4; ++e) {
            int qr = wid * 16 + g * 4 + e;
            outg[(size_t)qr * D + n * 16 + r16] = oacc[n][e];
        }
    }
}

} // namespace

extern "C" void kernel_launch(void* const* d_in, const int* in_sizes, int n_in,
                              void* d_out, int out_size, void* d_ws, size_t ws_size,
                              hipStream_t stream) {
    const float* q = (const float*)d_in[0];
    const float* k = (const float*)d_in[1];
    const float* v = (const float*)d_in[2];
    float* out  = (float*)d_out;
    float* attn = out + (size_t)BH * S * D;   // outputs concatenated: (out, attn)

    dim3 grid(S / QT, BH);
    sdpa_kernel<<<grid, 256, 0, stream>>>(q, k, v, out, attn);
}

// Round 3
// 203.553 us; speedup vs baseline: 1.4401x; 1.4401x over previous
//
#include <hip/hip_runtime.h>
#include <hip/hip_bf16.h>

namespace {

constexpr int S = 2048;
constexpr int D = 64;
constexpr int BH = 24;        // 2 batches * 12 heads
constexpr int QT = 64;        // q rows per block
constexpr int KT = 64;        // keys per tile
constexpr int NKT = S / KT;   // 32
// Row stride in ushorts. MUST keep rows 16B-aligned (144 B): PAD=66 (132 B)
// broke ds_read_b128/ds_write_b64 natural alignment -> silent corruption (R2).
constexpr int PAD = 72;

typedef __attribute__((ext_vector_type(8))) __bf16 bf16x8;
typedef __attribute__((ext_vector_type(4))) float  f32x4;
typedef __attribute__((ext_vector_type(4))) unsigned short u16x4;

__device__ inline unsigned short f2bf(float f) {
    unsigned int u = __float_as_uint(f);
    u += 0x7fffu + ((u >> 16) & 1u);
    return (unsigned short)(u >> 16);
}

__global__ __launch_bounds__(256, 3)
void sdpa_kernel(const float* __restrict__ q,
                 const float* __restrict__ k,
                 const float* __restrict__ v,
                 float* __restrict__ out,
                 float* __restrict__ attn) {
    __shared__ unsigned short Ks[2][KT][PAD];
    __shared__ unsigned short Vt[2][D][PAD];   // Vt[d][key]
    __shared__ unsigned short QPs[QT][PAD];    // Q staging, then P (rows wave-private)

    const int tid  = threadIdx.x;
    const int wid  = tid >> 6;       // wave 0..3 owns q rows [wid*16, wid*16+16)
    const int lane = tid & 63;
    const int g    = lane >> 4;      // 16-lane group
    const int r16  = lane & 15;      // q row within wave strip (swapped layout)
    const int bh   = blockIdx.y;
    const int q0   = blockIdx.x * QT;

    const float* qg = q + ((size_t)bh * S + q0) * D;
    const float* kg = k + (size_t)bh * S * D;
    const float* vg = v + (size_t)bh * S * D;
    float* attng = attn + ((size_t)bh * S + q0) * S;
    float* outg  = out  + ((size_t)bh * S + q0) * D;

    // ---- stage Q tile -> LDS (bf16), pull B-fragments into registers ----
    #pragma unroll
    for (int ii = 0; ii < 4; ++ii) {
        int idx = tid + ii * 256;
        int r = idx >> 4, c = (idx & 15) * 4;
        f32x4 f = *reinterpret_cast<const f32x4*>(qg + r * D + c);
        u16x4 w = { f2bf(f[0]), f2bf(f[1]), f2bf(f[2]), f2bf(f[3]) };
        *reinterpret_cast<u16x4*>(&QPs[r][c]) = w;
    }
    __syncthreads();
    // B-frag (swapped): lane holds Q[q = r16][d = g*8 + j]
    const bf16x8 bQ0 = *(const bf16x8*)&QPs[wid * 16 + r16][g * 8];
    const bf16x8 bQ1 = *(const bf16x8*)&QPs[wid * 16 + r16][32 + g * 8];

    // ================= phase 1: row sums of exp(scores/64) =================
    float rs = 0.0f;
    f32x4 pK[4];

    // prologue: tile 0 -> regs -> Ks[0]
    #pragma unroll
    for (int ii = 0; ii < 4; ++ii) {
        int idx = tid + ii * 256;
        int r = idx >> 4, c = (idx & 15) * 4;
        pK[ii] = *reinterpret_cast<const f32x4*>(kg + r * D + c);
    }
    #pragma unroll
    for (int ii = 0; ii < 4; ++ii) {
        int idx = tid + ii * 256;
        int r = idx >> 4, c = (idx & 15) * 4;
        u16x4 w = { f2bf(pK[ii][0]), f2bf(pK[ii][1]), f2bf(pK[ii][2]), f2bf(pK[ii][3]) };
        *reinterpret_cast<u16x4*>(&Ks[0][r][c]) = w;
    }
    __syncthreads();

    for (int t = 0; t < NKT; ++t) {
        const int cur = t & 1;
        if (t + 1 < NKT) {   // issue next tile's loads early (latency hides under compute)
            const float* ktg = kg + (size_t)(t + 1) * KT * D;
            #pragma unroll
            for (int ii = 0; ii < 4; ++ii) {
                int idx = tid + ii * 256;
                int r = idx >> 4, c = (idx & 15) * 4;
                pK[ii] = *reinterpret_cast<const f32x4*>(ktg + r * D + c);
            }
        }
        #pragma unroll
        for (int cf = 0; cf < 4; ++cf) {
            // A-frag: lane holds K[k = cf*16 + r16][d = g*8 + j]
            bf16x8 aK0 = *(const bf16x8*)&Ks[cur][cf * 16 + r16][g * 8];
            bf16x8 aK1 = *(const bf16x8*)&Ks[cur][cf * 16 + r16][32 + g * 8];
            f32x4 acc = {0.f, 0.f, 0.f, 0.f};
            acc = __builtin_amdgcn_mfma_f32_16x16x32_bf16(aK0, bQ0, acc, 0, 0, 0);
            acc = __builtin_amdgcn_mfma_f32_16x16x32_bf16(aK1, bQ1, acc, 0, 0, 0);
            // C[k][q]: lane holds q = r16, k = cf*16 + g*4 + e
            #pragma unroll
            for (int e = 0; e < 4; ++e)
                rs += __expf(acc[e] * (1.0f / 64.0f));
        }
        if (t + 1 < NKT) {
            const int nxt = (t + 1) & 1;
            #pragma unroll
            for (int ii = 0; ii < 4; ++ii) {
                int idx = tid + ii * 256;
                int r = idx >> 4, c = (idx & 15) * 4;
                u16x4 w = { f2bf(pK[ii][0]), f2bf(pK[ii][1]), f2bf(pK[ii][2]), f2bf(pK[ii][3]) };
                *reinterpret_cast<u16x4*>(&Ks[nxt][r][c]) = w;
            }
            __syncthreads();
        }
    }
    // sum over the 4 lane-groups holding the same q row
    rs += __shfl_xor(rs, 16, 64);
    rs += __shfl_xor(rs, 32, 64);
    const float inv = 1.0f / rs;

    // ====== phase 2: recompute scores, write attn (float4), accumulate PV ======
    f32x4 oacc[4];
    #pragma unroll
    for (int n = 0; n < 4; ++n) oacc[n] = {0.f, 0.f, 0.f, 0.f};

    f32x4 pV[4];
    const int vk0 = (tid & 15) * 4;   // V load: 4 rows x float4 (for transposed b64 writes)
    const int vc  = (tid >> 4) * 4;

    // prologue: tile 0 (K + V)
    #pragma unroll
    for (int ii = 0; ii < 4; ++ii) {
        int idx = tid + ii * 256;
        int r = idx >> 4, c = (idx & 15) * 4;
        pK[ii] = *reinterpret_cast<const f32x4*>(kg + r * D + c);
        pV[ii] = *reinterpret_cast<const f32x4*>(vg + (vk0 + ii) * D + vc);
    }
    #pragma unroll
    for (int ii = 0; ii < 4; ++ii) {
        int idx = tid + ii * 256;
        int r = idx >> 4, c = (idx & 15) * 4;
        u16x4 w = { f2bf(pK[ii][0]), f2bf(pK[ii][1]), f2bf(pK[ii][2]), f2bf(pK[ii][3]) };
        *reinterpret_cast<u16x4*>(&Ks[0][r][c]) = w;
    }
    #pragma unroll
    for (int j = 0; j < 4; ++j) {   // transposed: Vt[vc+j][vk0..vk0+3]
        u16x4 w = { f2bf(pV[0][j]), f2bf(pV[1][j]), f2bf(pV[2][j]), f2bf(pV[3][j]) };
        *reinterpret_cast<u16x4*>(&Vt[0][vc + j][vk0]) = w;
    }
    __syncthreads();

    for (int t = 0; t < NKT; ++t) {
        const int cur = t & 1;
        if (t + 1 < NKT) {
            const float* ktg = kg + (size_t)(t + 1) * KT * D;
            const float* vtg = vg + (size_t)(t + 1) * KT * D;
            #pragma unroll
            for (int ii = 0; ii < 4; ++ii) {
                int idx = tid + ii * 256;
                int r = idx >> 4, c = (idx & 15) * 4;
                pK[ii] = *reinterpret_cast<const f32x4*>(ktg + r * D + c);
                pV[ii] = *reinterpret_cast<const f32x4*>(vtg + (vk0 + ii) * D + vc);
            }
        }
        // QK^T (swapped) + normalized attn store + P -> LDS (wave-private rows)
        #pragma unroll
        for (int cf = 0; cf < 4; ++cf) {
            bf16x8 aK0 = *(const bf16x8*)&Ks[cur][cf * 16 + r16][g * 8];
            bf16x8 aK1 = *(const bf16x8*)&Ks[cur][cf * 16 + r16][32 + g * 8];
            f32x4 acc = {0.f, 0.f, 0.f, 0.f};
            acc = __builtin_amdgcn_mfma_f32_16x16x32_bf16(aK0, bQ0, acc, 0, 0, 0);
            acc = __builtin_amdgcn_mfma_f32_16x16x32_bf16(aK1, bQ1, acc, 0, 0, 0);
            f32x4 pst;
            u16x4 pb;
            #pragma unroll
            for (int e = 0; e < 4; ++e) {
                float p = __expf(acc[e] * (1.0f / 64.0f)) * inv;
                pst[e] = p;
                pb[e]  = f2bf(p);
            }
            // lane holds 4 consecutive k for q=r16 -> vector store
            *reinterpret_cast<f32x4*>(
                attng + (size_t)(wid * 16 + r16) * S + t * KT + cf * 16 + g * 4) = pst;
            *reinterpret_cast<u16x4*>(&QPs[wid * 16 + r16][cf * 16 + g * 4]) = pb;
        }
        // PV: A = P (own-wave rows just written; same-wave LDS dep)
        bf16x8 aP0 = *(const bf16x8*)&QPs[wid * 16 + r16][g * 8];
        bf16x8 aP1 = *(const bf16x8*)&QPs[wid * 16 + r16][32 + g * 8];
        #pragma unroll
        for (int n = 0; n < 4; ++n) {
            bf16x8 bv0 = *(const bf16x8*)&Vt[cur][n * 16 + r16][g * 8];
            bf16x8 bv1 = *(const bf16x8*)&Vt[cur][n * 16 + r16][32 + g * 8];
            oacc[n] = __builtin_amdgcn_mfma_f32_16x16x32_bf16(aP0, bv0, oacc[n], 0, 0, 0);
            oacc[n] = __builtin_amdgcn_mfma_f32_16x16x32_bf16(aP1, bv1, oacc[n], 0, 0, 0);
        }
        if (t + 1 < NKT) {
            const int nxt = (t + 1) & 1;
            #pragma unroll
            for (int ii = 0; ii < 4; ++ii) {
                int idx = tid + ii * 256;
                int r = idx >> 4, c = (idx & 15) * 4;
                u16x4 w = { f2bf(pK[ii][0]), f2bf(pK[ii][1]), f2bf(pK[ii][2]), f2bf(pK[ii][3]) };
                *reinterpret_cast<u16x4*>(&Ks[nxt][r][c]) = w;
            }
            #pragma unroll
            for (int j = 0; j < 4; ++j) {
                u16x4 w = { f2bf(pV[0][j]), f2bf(pV[1][j]), f2bf(pV[2][j]), f2bf(pV[3][j]) };
                *reinterpret_cast<u16x4*>(&Vt[nxt][vc + j][vk0]) = w;
            }
            __syncthreads();
        }
    }

    // ---- epilogue: out tile; C[q][d]: q = wid*16 + g*4 + e, d = n*16 + r16 ----
    #pragma unroll
    for (int n = 0; n < 4; ++n) {
        #pragma unroll
        for (int e = 0; e < 4; ++e) {
            outg[(size_t)(wid * 16 + g * 4 + e) * D + n * 16 + r16] = oacc[n][e];
        }
    }
}

} // namespace

extern "C" void kernel_launch(void* const* d_in, const int* in_sizes, int n_in,
                              void* d_out, int out_size, void* d_ws, size_t ws_size,
                              hipStream_t stream) {
    const float* q = (const float*)d_in[0];
    const float* k = (const float*)d_in[1];
    const float* v = (const float*)d_in[2];
    float* out  = (float*)d_out;
    float* attn = out + (size_t)BH * S * D;   // outputs concatenated: (out, attn)

    dim3 grid(S / QT, BH);
    sdpa_kernel<<<grid, 256, 0, stream>>>(q, k, v, out, attn);
}

// Round 4
// 141.366 us; speedup vs baseline: 2.0736x; 1.4399x over previous
//
#include <hip/hip_runtime.h>
#include <hip/hip_bf16.h>

namespace {

constexpr int S = 2048;
constexpr int D = 64;
constexpr int BH = 24;        // 2 batches * 12 heads
constexpr int QT = 64;        // q rows per block
constexpr int KT = 64;        // keys per tile
constexpr int NKT = S / KT;   // 32
// Row stride in ushorts. MUST keep rows 16B-aligned (144 B): PAD=66 (132 B)
// broke ds_read_b128/ds_write_b64 natural alignment -> silent corruption (R2).
constexpr int PAD = 72;

typedef __attribute__((ext_vector_type(8))) __bf16 bf16x8;
typedef __attribute__((ext_vector_type(4))) __bf16 bf16x4;
typedef __attribute__((ext_vector_type(4))) float  f32x4;

// f32x4 -> bf16x4 via native v_cvt_pk_bf16_f32 (RNE, 2 vals/inst)
__device__ inline bf16x4 cvt4(f32x4 f) {
    return __builtin_convertvector(f, bf16x4);
}

__global__ __launch_bounds__(256, 3)
void sdpa_kernel(const float* __restrict__ q,
                 const float* __restrict__ k,
                 const float* __restrict__ v,
                 float* __restrict__ out,
                 float* __restrict__ attn) {
    __shared__ unsigned short Ks[2][KT][PAD];
    __shared__ unsigned short Vt[2][D][PAD];   // Vt[d][key]
    __shared__ unsigned short QPs[QT][PAD];    // Q staging, then P (rows wave-private)

    const int tid  = threadIdx.x;
    const int wid  = tid >> 6;       // wave 0..3 owns q rows [wid*16, wid*16+16)
    const int lane = tid & 63;
    const int g    = lane >> 4;      // 16-lane group
    const int r16  = lane & 15;      // q row within wave strip (swapped layout)
    const int bh   = blockIdx.y;
    const int q0   = blockIdx.x * QT;

    const float* qg = q + ((size_t)bh * S + q0) * D;
    const float* kg = k + (size_t)bh * S * D;
    const float* vg = v + (size_t)bh * S * D;
    float* attng = attn + ((size_t)bh * S + q0) * S;
    float* outg  = out  + ((size_t)bh * S + q0) * D;

    // ---- stage Q tile -> LDS (bf16), pull B-fragments into registers ----
    #pragma unroll
    for (int ii = 0; ii < 4; ++ii) {
        int idx = tid + ii * 256;
        int r = idx >> 4, c = (idx & 15) * 4;
        f32x4 f = *reinterpret_cast<const f32x4*>(qg + r * D + c);
        *reinterpret_cast<bf16x4*>(&QPs[r][c]) = cvt4(f);
    }
    __syncthreads();
    // B-frag (swapped): lane holds Q[q = r16][d = g*8 + j]
    const bf16x8 bQ0 = *(const bf16x8*)&QPs[wid * 16 + r16][g * 8];
    const bf16x8 bQ1 = *(const bf16x8*)&QPs[wid * 16 + r16][32 + g * 8];

    // ================= phase 1: row sums of exp(scores/64) =================
    float rs = 0.0f;
    f32x4 pK[4];

    // prologue: tile 0 -> regs -> Ks[0]
    #pragma unroll
    for (int ii = 0; ii < 4; ++ii) {
        int idx = tid + ii * 256;
        int r = idx >> 4, c = (idx & 15) * 4;
        pK[ii] = *reinterpret_cast<const f32x4*>(kg + r * D + c);
    }
    #pragma unroll
    for (int ii = 0; ii < 4; ++ii) {
        int idx = tid + ii * 256;
        int r = idx >> 4, c = (idx & 15) * 4;
        *reinterpret_cast<bf16x4*>(&Ks[0][r][c]) = cvt4(pK[ii]);
    }
    __syncthreads();

    for (int t = 0; t < NKT; ++t) {
        const int cur = t & 1;
        if (t + 1 < NKT) {   // issue next tile's loads early (latency hides under compute)
            const float* ktg = kg + (size_t)(t + 1) * KT * D;
            #pragma unroll
            for (int ii = 0; ii < 4; ++ii) {
                int idx = tid + ii * 256;
                int r = idx >> 4, c = (idx & 15) * 4;
                pK[ii] = *reinterpret_cast<const f32x4*>(ktg + r * D + c);
            }
        }
        #pragma unroll
        for (int cf = 0; cf < 4; ++cf) {
            // A-frag: lane holds K[k = cf*16 + r16][d = g*8 + j]
            bf16x8 aK0 = *(const bf16x8*)&Ks[cur][cf * 16 + r16][g * 8];
            bf16x8 aK1 = *(const bf16x8*)&Ks[cur][cf * 16 + r16][32 + g * 8];
            f32x4 acc = {0.f, 0.f, 0.f, 0.f};
            acc = __builtin_amdgcn_mfma_f32_16x16x32_bf16(aK0, bQ0, acc, 0, 0, 0);
            acc = __builtin_amdgcn_mfma_f32_16x16x32_bf16(aK1, bQ1, acc, 0, 0, 0);
            // C[k][q]: lane holds q = r16, k = cf*16 + g*4 + e
            #pragma unroll
            for (int e = 0; e < 4; ++e)
                rs += __expf(acc[e] * (1.0f / 64.0f));
        }
        if (t + 1 < NKT) {
            const int nxt = (t + 1) & 1;
            #pragma unroll
            for (int ii = 0; ii < 4; ++ii) {
                int idx = tid + ii * 256;
                int r = idx >> 4, c = (idx & 15) * 4;
                *reinterpret_cast<bf16x4*>(&Ks[nxt][r][c]) = cvt4(pK[ii]);
            }
            __syncthreads();
        }
    }
    // sum over the 4 lane-groups holding the same q row
    rs += __shfl_xor(rs, 16, 64);
    rs += __shfl_xor(rs, 32, 64);
    const float inv = 1.0f / rs;

    // ====== phase 2: recompute scores, write attn (float4), accumulate PV ======
    f32x4 oacc[4];
    #pragma unroll
    for (int n = 0; n < 4; ++n) oacc[n] = {0.f, 0.f, 0.f, 0.f};

    f32x4 pV[4];
    const int vk0 = (tid & 15) * 4;   // V load: 4 rows x float4 (for transposed b64 writes)
    const int vc  = (tid >> 4) * 4;

    // prologue: tile 0 (K + V)
    #pragma unroll
    for (int ii = 0; ii < 4; ++ii) {
        int idx = tid + ii * 256;
        int r = idx >> 4, c = (idx & 15) * 4;
        pK[ii] = *reinterpret_cast<const f32x4*>(kg + r * D + c);
        pV[ii] = *reinterpret_cast<const f32x4*>(vg + (vk0 + ii) * D + vc);
    }
    #pragma unroll
    for (int ii = 0; ii < 4; ++ii) {
        int idx = tid + ii * 256;
        int r = idx >> 4, c = (idx & 15) * 4;
        *reinterpret_cast<bf16x4*>(&Ks[0][r][c]) = cvt4(pK[ii]);
    }
    #pragma unroll
    for (int j = 0; j < 4; ++j) {   // transposed: Vt[vc+j][vk0..vk0+3]
        f32x4 col = { pV[0][j], pV[1][j], pV[2][j], pV[3][j] };
        *reinterpret_cast<bf16x4*>(&Vt[0][vc + j][vk0]) = cvt4(col);
    }
    __syncthreads();

    for (int t = 0; t < NKT; ++t) {
        const int cur = t & 1;
        if (t + 1 < NKT) {
            const float* ktg = kg + (size_t)(t + 1) * KT * D;
            const float* vtg = vg + (size_t)(t + 1) * KT * D;
            #pragma unroll
            for (int ii = 0; ii < 4; ++ii) {
                int idx = tid + ii * 256;
                int r = idx >> 4, c = (idx & 15) * 4;
                pK[ii] = *reinterpret_cast<const f32x4*>(ktg + r * D + c);
                pV[ii] = *reinterpret_cast<const f32x4*>(vtg + (vk0 + ii) * D + vc);
            }
        }
        // QK^T (swapped) + normalized attn store + P -> LDS (wave-private rows)
        #pragma unroll
        for (int cf = 0; cf < 4; ++cf) {
            bf16x8 aK0 = *(const bf16x8*)&Ks[cur][cf * 16 + r16][g * 8];
            bf16x8 aK1 = *(const bf16x8*)&Ks[cur][cf * 16 + r16][32 + g * 8];
            f32x4 acc = {0.f, 0.f, 0.f, 0.f};
            acc = __builtin_amdgcn_mfma_f32_16x16x32_bf16(aK0, bQ0, acc, 0, 0, 0);
            acc = __builtin_amdgcn_mfma_f32_16x16x32_bf16(aK1, bQ1, acc, 0, 0, 0);
            f32x4 pst;
            #pragma unroll
            for (int e = 0; e < 4; ++e)
                pst[e] = __expf(acc[e] * (1.0f / 64.0f)) * inv;
            // lane holds 4 consecutive k for q=r16 -> vector store (non-temporal:
            // the 403MB attn stream is never re-read; don't evict K/V from L2/L3)
            __builtin_nontemporal_store(pst, reinterpret_cast<f32x4*>(
                attng + (size_t)(wid * 16 + r16) * S + t * KT + cf * 16 + g * 4));
            *reinterpret_cast<bf16x4*>(&QPs[wid * 16 + r16][cf * 16 + g * 4]) = cvt4(pst);
        }
        // PV: A = P (own-wave rows just written; same-wave LDS dep)
        bf16x8 aP0 = *(const bf16x8*)&QPs[wid * 16 + r16][g * 8];
        bf16x8 aP1 = *(const bf16x8*)&QPs[wid * 16 + r16][32 + g * 8];
        #pragma unroll
        for (int n = 0; n < 4; ++n) {
            bf16x8 bv0 = *(const bf16x8*)&Vt[cur][n * 16 + r16][g * 8];
            bf16x8 bv1 = *(const bf16x8*)&Vt[cur][n * 16 + r16][32 + g * 8];
            oacc[n] = __builtin_amdgcn_mfma_f32_16x16x32_bf16(aP0, bv0, oacc[n], 0, 0, 0);
            oacc[n] = __builtin_amdgcn_mfma_f32_16x16x32_bf16(aP1, bv1, oacc[n], 0, 0, 0);
        }
        if (t + 1 < NKT) {
            const int nxt = (t + 1) & 1;
            #pragma unroll
            for (int ii = 0; ii < 4; ++ii) {
                int idx = tid + ii * 256;
                int r = idx >> 4, c = (idx & 15) * 4;
                *reinterpret_cast<bf16x4*>(&Ks[nxt][r][c]) = cvt4(pK[ii]);
            }
            #pragma unroll
            for (int j = 0; j < 4; ++j) {
                f32x4 col = { pV[0][j], pV[1][j], pV[2][j], pV[3][j] };
                *reinterpret_cast<bf16x4*>(&Vt[nxt][vc + j][vk0]) = cvt4(col);
            }
            __syncthreads();
        }
    }

    // ---- epilogue: out tile; C[q][d]: q = wid*16 + g*4 + e, d = n*16 + r16 ----
    #pragma unroll
    for (int n = 0; n < 4; ++n) {
        #pragma unroll
        for (int e = 0; e < 4; ++e) {
            __builtin_nontemporal_store(oacc[n][e],
                outg + (size_t)(wid * 16 + g * 4 + e) * D + n * 16 + r16);
        }
    }
}

} // namespace

extern "C" void kernel_launch(void* const* d_in, const int* in_sizes, int n_in,
                              void* d_out, int out_size, void* d_ws, size_t ws_size,
                              hipStream_t stream) {
    const float* q = (const float*)d_in[0];
    const float* k = (const float*)d_in[1];
    const float* v = (const float*)d_in[2];
    float* out  = (float*)d_out;
    float* attn = out + (size_t)BH * S * D;   // outputs concatenated: (out, attn)

    dim3 grid(S / QT, BH);
    sdpa_kernel<<<grid, 256, 0, stream>>>(q, k, v, out, attn);
}